// Round 9
// baseline (153.326 us; speedup 1.0000x reference)
//
#include <hip/hip_runtime.h>
#include <hip/hip_cooperative_groups.h>
#include <cfloat>

namespace cg = cooperative_groups;

// Chamfer L1, pred [B,N,3], gt [B,M,3] fp32, N==M==4096, B==4.
// R9: single cooperative dispatch. R8 (71.4us) budget: fill 40.6 + fixed
//     graph ~10 + partial ~15 + reduce 2.5 + 1 dispatch gap 1.4.
//     Fuse reduce into the partial kernel with cg::this_grid().sync():
//     phase 1 = R8's partial (plain coalesced stores — NOT R3's atomicMin/
//     threadfence design), phase 2 = 128 parallel blocks doing the 32-chunk
//     min + sum (NOT R3's single serial block). Saves the inter-dispatch gap
//     and the reduce launch tail; grid.sync handles cross-XCD visibility.
//     Phase-1 loop unchanged: 512 blocks (2/CU), PTS=8, MC=128, SoA LDS,
//     register-pipelined broadcast reads, asm-pinned 5.5 VALU/target.

constexpr int TPB = 256;
constexpr int PTS = 8;            // query points per thread
constexpr int NC  = TPB * PTS;    // 2048 queries per block
constexpr int MC  = 128;          // targets staged in LDS per block

__global__ __launch_bounds__(TPB) void chamfer_fused_kernel(
    const float* __restrict__ pred, const float* __restrict__ gt,
    float* __restrict__ partial, float* __restrict__ out,
    int B, int N, int M, float inv) {
    const int dir = blockIdx.z;
    const int b   = blockIdx.y;
    const float* q = dir ? gt   : pred;
    const float* t = dir ? pred : gt;
    const int Nq   = dir ? M : N;
    const int Nt   = dir ? N : M;
    const int nchunks = Nq / NC;              // 2
    const int nc = blockIdx.x % nchunks;
    const int mc = blockIdx.x / nchunks;      // 0..Nt/MC-1 (31)

    // Zero-init out before the grid barrier; agent-scope store so the
    // post-sync atomicAdds (other XCDs) can't see a stale line.
    if (blockIdx.x == 0 && blockIdx.y == 0 && blockIdx.z == 0 && threadIdx.x == 0)
        __hip_atomic_store(out, 0.0f, __ATOMIC_RELAXED, __HIP_MEMORY_SCOPE_AGENT);

    __shared__ __align__(16) float ldsx[MC];  // SoA: 3 x 512 B
    __shared__ __align__(16) float ldsy[MC];
    __shared__ __align__(16) float ldsz[MC];
    __shared__ float red[4];

    // Query loads first — vmcnt wait lands after staging+barrier.
    const float* qb = q + (size_t)b * Nq * 3;
    float px[PTS], py[PTS], pz[PTS], mn[PTS];
    int n[PTS];
#pragma unroll
    for (int i = 0; i < PTS; ++i) {
        n[i] = nc * NC + threadIdx.x + i * TPB;
        px[i] = qb[n[i] * 3 + 0];
        py[i] = qb[n[i] * 3 + 1];
        pz[i] = qb[n[i] * 3 + 2];
        mn[i] = FLT_MAX;
    }

    // Stage target chunk (128 pts x 12 B) into LDS, AoS->SoA transpose.
    const float* tbase = t + ((size_t)b * Nt + (size_t)mc * MC) * 3;
    for (int i = threadIdx.x; i < MC * 3; i += TPB) {
        const int c = i % 3, p = i / 3;
        (c == 0 ? ldsx : c == 1 ? ldsy : ldsz)[p] = tbase[i];
    }
    __syncthreads();

    // Register-pipelined j-loop: 4 targets/iter, next iter's 3 broadcast
    // ds_read_b128 issued before this iter's 176 asm VALU ops.
    const float4* lx4 = (const float4*)ldsx;
    const float4* ly4 = (const float4*)ldsy;
    const float4* lz4 = (const float4*)ldsz;
    constexpr int NIT = MC / 4;               // 32
    float4 gx = lx4[0], gy = ly4[0], gz = lz4[0];
#pragma unroll 2
    for (int j4 = 0; j4 < NIT; ++j4) {
        const int jn = (j4 + 1) & (NIT - 1);  // branchless wrap (1 wasted read)
        float4 nx = lx4[jn], ny = ly4[jn], nz = lz4[jn];
#pragma unroll
        for (int i = 0; i < PTS; ++i) {
            float dx0 = px[i] - gx.x, dy0 = py[i] - gy.x, dz0 = pz[i] - gz.x;
            float dx1 = px[i] - gx.y, dy1 = py[i] - gy.y, dz1 = pz[i] - gz.y;
            float dx2 = px[i] - gx.z, dy2 = py[i] - gy.z, dz2 = pz[i] - gz.z;
            float dx3 = px[i] - gx.w, dy3 = py[i] - gy.w, dz3 = pz[i] - gz.w;
            float s0, s1, s2, s3, d0, d1, d2, d3;
            asm("v_add_f32_e64 %0, |%1|, |%2|" : "=v"(s0) : "v"(dx0), "v"(dy0));
            asm("v_add_f32_e64 %0, %1, |%2|"   : "=v"(d0) : "v"(s0),  "v"(dz0));
            asm("v_add_f32_e64 %0, |%1|, |%2|" : "=v"(s1) : "v"(dx1), "v"(dy1));
            asm("v_add_f32_e64 %0, %1, |%2|"   : "=v"(d1) : "v"(s1),  "v"(dz1));
            asm("v_add_f32_e64 %0, |%1|, |%2|" : "=v"(s2) : "v"(dx2), "v"(dy2));
            asm("v_add_f32_e64 %0, %1, |%2|"   : "=v"(d2) : "v"(s2),  "v"(dz2));
            asm("v_add_f32_e64 %0, |%1|, |%2|" : "=v"(s3) : "v"(dx3), "v"(dy3));
            asm("v_add_f32_e64 %0, %1, |%2|"   : "=v"(d3) : "v"(s3),  "v"(dz3));
            asm("v_min3_f32 %0, %0, %1, %2"    : "+v"(mn[i]) : "v"(d0), "v"(d1));
            asm("v_min3_f32 %0, %0, %1, %2"    : "+v"(mn[i]) : "v"(d2), "v"(d3));
        }
        gx = nx; gy = ny; gz = nz;
    }

    // partial[mc][dir][b][n] — plain coalesced stores (N==M for stride).
    float* outp = partial + (((size_t)mc * 2 + dir) * B + b) * N;
#pragma unroll
    for (int i = 0; i < PTS; ++i) outp[n[i]] = mn[i];

    // ---- grid-wide barrier (execution + device memory visibility) ----
    cg::this_grid().sync();

    // Phase 2: 128 blocks x 256 threads = 1 thread per query.
    const int linear = blockIdx.x + gridDim.x * (blockIdx.y + gridDim.y * blockIdx.z);
    if (linear >= 128) return;
    const int Q = 2 * B * N;                  // 32768
    const int qidx = linear * TPB + threadIdx.x;
    float mnq = FLT_MAX;
#pragma unroll
    for (int mc2 = 0; mc2 < 32; ++mc2)        // nmc == 32 for MC==128
        mnq = fminf(mnq, partial[(size_t)mc2 * Q + qidx]);
    float v = mnq * inv;

    // wave-64 shuffle reduce, then cross-wave via LDS
    for (int off = 32; off > 0; off >>= 1) v += __shfl_down(v, off, 64);
    const int lane = threadIdx.x & 63, w = threadIdx.x >> 6;
    if (lane == 0) red[w] = v;
    __syncthreads();
    if (threadIdx.x == 0)
        atomicAdd(out, red[0] + red[1] + red[2] + red[3]);
}

extern "C" void kernel_launch(void* const* d_in, const int* in_sizes, int n_in,
                              void* d_out, int out_size, void* d_ws, size_t ws_size,
                              hipStream_t stream) {
    const float* pred = (const float*)d_in[0];
    const float* gt   = (const float*)d_in[1];
    float* out = (float*)d_out;

    const int B = 4;
    const int N = in_sizes[0] / (B * 3);   // 4096
    const int M = in_sizes[1] / (B * 3);   // 4096

    float* partial = (float*)d_ws;          // [32][2][B][N] floats = 4 MB

    dim3 grid((N / NC) * (M / MC), B, 2);   // 64 x 4 x 2 = 512 blocks
    dim3 block(TPB);
    float inv = 1.0f / (float)(B * N);      // equal for both dirs since N==M

    void* args[] = {(void*)&pred, (void*)&gt, (void*)&partial, (void*)&out,
                    (void*)&B, (void*)&N, (void*)&M, (void*)&inv};
    hipLaunchCooperativeKernel((void*)chamfer_fused_kernel, grid, block,
                               args, 0, stream);
}

// Round 10
// 75.650 us; speedup vs baseline: 2.0268x; 2.0268x over previous
//
#include <hip/hip_runtime.h>
#include <cfloat>

// Chamfer L1, pred [B,N,3], gt [B,M,3] fp32, N==M==4096, B==4.
// R10: R8 anchor (71.4us; 2 dispatches, 512 blocks = 2/CU, PTS=8, MC=128,
//      SoA LDS, out zero-init in kernel 1). R9's cooperative grid.sync was
//      a disaster (kernel 79us) — reverted. Single change vs R8: pack the
//      3 subs/target across TARGET PAIRS with v_pk_add_f32 (VOP3P, gfx90a+
//      packed fp32; SoA makes target coords adjacent):
//        per 2 targets: 3 pk_sub + 4 add(|.|) + 1 min3 = 8 VALU
//        -> 4.0 VALU/target (was 5.5) -> VALU term 9.4 -> 6.8us.
//      Also dropped R8's mov-based pipeline (12 movs/iter, measured ~null)
//      for plain unroll-2; compiler hoists the independent LDS reads.

constexpr int TPB = 256;
constexpr int PTS = 8;            // query points per thread
constexpr int NC  = TPB * PTS;    // 2048 queries per block
constexpr int MC  = 128;          // targets staged in LDS per block

typedef float f32x2 __attribute__((ext_vector_type(2)));

__global__ __launch_bounds__(TPB) void chamfer_partial_kernel(
    const float* __restrict__ pred, const float* __restrict__ gt,
    float* __restrict__ partial, float* __restrict__ out,
    int B, int N, int M) {
    const int dir = blockIdx.z;
    const int b   = blockIdx.y;
    const float* q = dir ? gt   : pred;
    const float* t = dir ? pred : gt;
    const int Nq   = dir ? M : N;
    const int Nt   = dir ? N : M;
    const int nchunks = Nq / NC;              // 2
    const int nc = blockIdx.x % nchunks;
    const int mc = blockIdx.x / nchunks;      // 0..Nt/MC-1 (31)

    // In-kernel zero-init of the output accumulator (replaces memset).
    if (blockIdx.x == 0 && blockIdx.y == 0 && blockIdx.z == 0 && threadIdx.x == 0)
        *out = 0.0f;

    __shared__ __align__(16) float ldsx[MC];  // SoA: 3 x 512 B
    __shared__ __align__(16) float ldsy[MC];
    __shared__ __align__(16) float ldsz[MC];

    // Query loads first — vmcnt wait lands after staging+barrier.
    const float* qb = q + (size_t)b * Nq * 3;
    float px[PTS], py[PTS], pz[PTS], mn[PTS];
    int n[PTS];
#pragma unroll
    for (int i = 0; i < PTS; ++i) {
        n[i] = nc * NC + threadIdx.x + i * TPB;
        px[i] = qb[n[i] * 3 + 0];
        py[i] = qb[n[i] * 3 + 1];
        pz[i] = qb[n[i] * 3 + 2];
        mn[i] = FLT_MAX;
    }

    // Stage target chunk (128 pts x 12 B) into LDS, AoS->SoA transpose.
    const float* tbase = t + ((size_t)b * Nt + (size_t)mc * MC) * 3;
    for (int i = threadIdx.x; i < MC * 3; i += TPB) {
        const int c = i % 3, p = i / 3;
        (c == 0 ? ldsx : c == 1 ? ldsy : ldsz)[p] = tbase[i];
    }
    __syncthreads();

    // Broadcast query coords into register pairs for VOP3P (setup once).
    f32x2 px2[PTS], py2[PTS], pz2[PTS];
#pragma unroll
    for (int i = 0; i < PTS; ++i) {
        px2[i] = (f32x2){px[i], px[i]};
        py2[i] = (f32x2){py[i], py[i]};
        pz2[i] = (f32x2){pz[i], pz[i]};
    }

    // One pair of targets against query i: 3 pk_sub + 4 add(|.|) + 1 min3.
#define PAIR_STEP(GX, GY, GZ, i)                                               \
    {                                                                          \
        f32x2 dx, dy, dz; float s0, s1, d0, d1;                                \
        asm("v_pk_add_f32 %0, %1, %2 neg_lo:[0,1] neg_hi:[0,1]"                \
            : "=v"(dx) : "v"(px2[i]), "v"(GX));                                \
        asm("v_pk_add_f32 %0, %1, %2 neg_lo:[0,1] neg_hi:[0,1]"                \
            : "=v"(dy) : "v"(py2[i]), "v"(GY));                                \
        asm("v_pk_add_f32 %0, %1, %2 neg_lo:[0,1] neg_hi:[0,1]"                \
            : "=v"(dz) : "v"(pz2[i]), "v"(GZ));                                \
        asm("v_add_f32_e64 %0, |%1|, |%2|" : "=v"(s0) : "v"(dx.x), "v"(dy.x)); \
        asm("v_add_f32_e64 %0, |%1|, |%2|" : "=v"(s1) : "v"(dx.y), "v"(dy.y)); \
        asm("v_add_f32_e64 %0, %1, |%2|"   : "=v"(d0) : "v"(s0), "v"(dz.x));   \
        asm("v_add_f32_e64 %0, %1, |%2|"   : "=v"(d1) : "v"(s1), "v"(dz.y));   \
        asm("v_min3_f32 %0, %0, %1, %2"    : "+v"(mn[i]) : "v"(d0), "v"(d1));  \
    }

    // 4 targets per iter: 3 broadcast ds_read_b128 -> two coord-pairs each.
    const float4* lx4 = (const float4*)ldsx;
    const float4* ly4 = (const float4*)ldsy;
    const float4* lz4 = (const float4*)ldsz;
    constexpr int NIT = MC / 4;               // 32
#pragma unroll 2
    for (int j4 = 0; j4 < NIT; ++j4) {
        float4 ax = lx4[j4], ay = ly4[j4], az = lz4[j4];
        f32x2 x01 = {ax.x, ax.y}, x23 = {ax.z, ax.w};
        f32x2 y01 = {ay.x, ay.y}, y23 = {ay.z, ay.w};
        f32x2 z01 = {az.x, az.y}, z23 = {az.z, az.w};
#pragma unroll
        for (int i = 0; i < PTS; ++i) {
            PAIR_STEP(x01, y01, z01, i)
            PAIR_STEP(x23, y23, z23, i)
        }
    }
#undef PAIR_STEP

    // partial[mc][dir][b][n] — coalesced stores (N==M assumed for stride).
    float* outp = partial + (((size_t)mc * 2 + dir) * B + b) * N;
#pragma unroll
    for (int i = 0; i < PTS; ++i) outp[n[i]] = mn[i];
}

__global__ __launch_bounds__(256) void chamfer_reduce_kernel(
    const float* __restrict__ partial, float* __restrict__ out,
    int Q, float inv) {
    const int qidx = blockIdx.x * 256 + threadIdx.x;
    float mn = FLT_MAX;
#pragma unroll
    for (int mc = 0; mc < 32; ++mc)   // nmc == 32 for N==M==4096, MC==128
        mn = fminf(mn, partial[(size_t)mc * Q + qidx]);
    float v = mn * inv;

    // wave-64 shuffle reduce, then cross-wave via LDS
    for (int off = 32; off > 0; off >>= 1) v += __shfl_down(v, off, 64);
    __shared__ float red[4];
    const int lane = threadIdx.x & 63, w = threadIdx.x >> 6;
    if (lane == 0) red[w] = v;
    __syncthreads();
    if (threadIdx.x == 0)
        atomicAdd(out, red[0] + red[1] + red[2] + red[3]);
}

extern "C" void kernel_launch(void* const* d_in, const int* in_sizes, int n_in,
                              void* d_out, int out_size, void* d_ws, size_t ws_size,
                              hipStream_t stream) {
    const float* pred = (const float*)d_in[0];
    const float* gt   = (const float*)d_in[1];
    float* out = (float*)d_out;

    const int B = 4;
    const int N = in_sizes[0] / (B * 3);   // 4096
    const int M = in_sizes[1] / (B * 3);   // 4096

    float* partial = (float*)d_ws;          // [32][2][B][N] floats = 4 MB
    const int Q = 2 * B * N;                // 32768

    dim3 grid((N / NC) * (M / MC), B, 2);   // 64 x 4 x 2 = 512 blocks
    chamfer_partial_kernel<<<grid, TPB, 0, stream>>>(pred, gt, partial, out, B, N, M);

    // mean scale: 1/(B*N) for dir0, 1/(B*M) for dir1 — equal since N==M.
    chamfer_reduce_kernel<<<Q / 256, 256, 0, stream>>>(
        partial, out, Q, 1.0f / (float)(B * N));
}

// Round 11
// 71.601 us; speedup vs baseline: 2.1414x; 1.0566x over previous
//
#include <hip/hip_runtime.h>
#include <cfloat>

// Chamfer L1, pred [B,N,3], gt [B,M,3] fp32, N==M==4096, B==4.
// R11: revert to R8 (measured 71.4us best) — R9 coop-sync (153us) and R10
//      v_pk_add_f32 (75.7us; VOP3P half-rate or pair-marshalling movs) both
//      regressed. Partial kernel below is byte-identical to R8:
//      2 dispatches, 512 blocks = 2/CU, PTS=8, MC=128, SoA LDS, register-
//      pipelined broadcast ds_read_b128, asm-pinned 5.5 VALU/target
//      (3 sub + 2 add|.| + 0.5 min3), out zero-init in kernel 1.
//      Single change: reduce kernel vectorized — each thread owns 4
//      consecutive queries (float4 loads, componentwise min over 32 chunks,
//      then sum components; valid since all query mins feed one scaled sum).

constexpr int TPB = 256;
constexpr int PTS = 8;            // query points per thread
constexpr int NC  = TPB * PTS;    // 2048 queries per block
constexpr int MC  = 128;          // targets staged in LDS per block

__global__ __launch_bounds__(TPB) void chamfer_partial_kernel(
    const float* __restrict__ pred, const float* __restrict__ gt,
    float* __restrict__ partial, float* __restrict__ out,
    int B, int N, int M) {
    const int dir = blockIdx.z;
    const int b   = blockIdx.y;
    const float* q = dir ? gt   : pred;
    const float* t = dir ? pred : gt;
    const int Nq   = dir ? M : N;
    const int Nt   = dir ? N : M;
    const int nchunks = Nq / NC;              // 2
    const int nc = blockIdx.x % nchunks;
    const int mc = blockIdx.x / nchunks;      // 0..Nt/MC-1 (31)

    // In-kernel zero-init of the output accumulator (replaces memset).
    if (blockIdx.x == 0 && blockIdx.y == 0 && blockIdx.z == 0 && threadIdx.x == 0)
        *out = 0.0f;

    __shared__ __align__(16) float ldsx[MC];  // SoA: 3 x 512 B
    __shared__ __align__(16) float ldsy[MC];
    __shared__ __align__(16) float ldsz[MC];

    // Query loads first — vmcnt wait lands after staging+barrier.
    const float* qb = q + (size_t)b * Nq * 3;
    float px[PTS], py[PTS], pz[PTS], mn[PTS];
    int n[PTS];
#pragma unroll
    for (int i = 0; i < PTS; ++i) {
        n[i] = nc * NC + threadIdx.x + i * TPB;
        px[i] = qb[n[i] * 3 + 0];
        py[i] = qb[n[i] * 3 + 1];
        pz[i] = qb[n[i] * 3 + 2];
        mn[i] = FLT_MAX;
    }

    // Stage target chunk (128 pts x 12 B) into LDS, AoS->SoA transpose.
    const float* tbase = t + ((size_t)b * Nt + (size_t)mc * MC) * 3;
    for (int i = threadIdx.x; i < MC * 3; i += TPB) {
        const int c = i % 3, p = i / 3;
        (c == 0 ? ldsx : c == 1 ? ldsy : ldsz)[p] = tbase[i];
    }
    __syncthreads();

    // Register-pipelined j-loop: 4 targets per iter, 3 broadcast
    // ds_read_b128 for iter j+1 issued before iter j's 176 VALU ops.
    const float4* lx4 = (const float4*)ldsx;
    const float4* ly4 = (const float4*)ldsy;
    const float4* lz4 = (const float4*)ldsz;
    constexpr int NIT = MC / 4;               // 32
    float4 gx = lx4[0], gy = ly4[0], gz = lz4[0];
#pragma unroll 2
    for (int j4 = 0; j4 < NIT; ++j4) {
        const int jn = (j4 + 1) & (NIT - 1);  // branchless wrap (1 wasted read)
        float4 nx = lx4[jn], ny = ly4[jn], nz = lz4[jn];
#pragma unroll
        for (int i = 0; i < PTS; ++i) {
            float dx0 = px[i] - gx.x, dy0 = py[i] - gy.x, dz0 = pz[i] - gz.x;
            float dx1 = px[i] - gx.y, dy1 = py[i] - gy.y, dz1 = pz[i] - gz.y;
            float dx2 = px[i] - gx.z, dy2 = py[i] - gy.z, dz2 = pz[i] - gz.z;
            float dx3 = px[i] - gx.w, dy3 = py[i] - gy.w, dz3 = pz[i] - gz.w;
            float s0, s1, s2, s3, d0, d1, d2, d3;
            asm("v_add_f32_e64 %0, |%1|, |%2|" : "=v"(s0) : "v"(dx0), "v"(dy0));
            asm("v_add_f32_e64 %0, %1, |%2|"   : "=v"(d0) : "v"(s0),  "v"(dz0));
            asm("v_add_f32_e64 %0, |%1|, |%2|" : "=v"(s1) : "v"(dx1), "v"(dy1));
            asm("v_add_f32_e64 %0, %1, |%2|"   : "=v"(d1) : "v"(s1),  "v"(dz1));
            asm("v_add_f32_e64 %0, |%1|, |%2|" : "=v"(s2) : "v"(dx2), "v"(dy2));
            asm("v_add_f32_e64 %0, %1, |%2|"   : "=v"(d2) : "v"(s2),  "v"(dz2));
            asm("v_add_f32_e64 %0, |%1|, |%2|" : "=v"(s3) : "v"(dx3), "v"(dy3));
            asm("v_add_f32_e64 %0, %1, |%2|"   : "=v"(d3) : "v"(s3),  "v"(dz3));
            asm("v_min3_f32 %0, %0, %1, %2"    : "+v"(mn[i]) : "v"(d0), "v"(d1));
            asm("v_min3_f32 %0, %0, %1, %2"    : "+v"(mn[i]) : "v"(d2), "v"(d3));
        }
        gx = nx; gy = ny; gz = nz;
    }

    // partial[mc][dir][b][n] — coalesced stores (N==M assumed for stride).
    float* outp = partial + (((size_t)mc * 2 + dir) * B + b) * N;
#pragma unroll
    for (int i = 0; i < PTS; ++i) outp[n[i]] = mn[i];
}

__global__ __launch_bounds__(256) void chamfer_reduce_kernel(
    const float* __restrict__ partial, float* __restrict__ out,
    int Q, float inv) {
    // Each thread owns 4 consecutive queries via float4 loads.
    const int q4 = blockIdx.x * 256 + threadIdx.x;   // float4 index
    const float4* p4 = (const float4*)partial;
    float4 mn4 = {FLT_MAX, FLT_MAX, FLT_MAX, FLT_MAX};
#pragma unroll
    for (int mc = 0; mc < 32; ++mc) {   // nmc == 32 for N==M==4096, MC==128
        float4 v = p4[(size_t)mc * (Q / 4) + q4];
        mn4.x = fminf(mn4.x, v.x);
        mn4.y = fminf(mn4.y, v.y);
        mn4.z = fminf(mn4.z, v.z);
        mn4.w = fminf(mn4.w, v.w);
    }
    float v = (mn4.x + mn4.y + mn4.z + mn4.w) * inv;

    // wave-64 shuffle reduce, then cross-wave via LDS
    for (int off = 32; off > 0; off >>= 1) v += __shfl_down(v, off, 64);
    __shared__ float red[4];
    const int lane = threadIdx.x & 63, w = threadIdx.x >> 6;
    if (lane == 0) red[w] = v;
    __syncthreads();
    if (threadIdx.x == 0)
        atomicAdd(out, red[0] + red[1] + red[2] + red[3]);
}

extern "C" void kernel_launch(void* const* d_in, const int* in_sizes, int n_in,
                              void* d_out, int out_size, void* d_ws, size_t ws_size,
                              hipStream_t stream) {
    const float* pred = (const float*)d_in[0];
    const float* gt   = (const float*)d_in[1];
    float* out = (float*)d_out;

    const int B = 4;
    const int N = in_sizes[0] / (B * 3);   // 4096
    const int M = in_sizes[1] / (B * 3);   // 4096

    float* partial = (float*)d_ws;          // [32][2][B][N] floats = 4 MB
    const int Q = 2 * B * N;                // 32768

    dim3 grid((N / NC) * (M / MC), B, 2);   // 64 x 4 x 2 = 512 blocks
    chamfer_partial_kernel<<<grid, TPB, 0, stream>>>(pred, gt, partial, out, B, N, M);

    // mean scale: 1/(B*N) for dir0, 1/(B*M) for dir1 — equal since N==M.
    chamfer_reduce_kernel<<<Q / 4 / 256, 256, 0, stream>>>(
        partial, out, Q, 1.0f / (float)(B * N));
}